// Round 6
// baseline (309.245 us; speedup 1.0000x reference)
//
#include <hip/hip_runtime.h>

#define SELU_SCALE 1.0507009873554805f
#define SELU_ALPHA 1.6732632423543772f

typedef __attribute__((ext_vector_type(8))) short short8;
typedef __attribute__((ext_vector_type(4))) float f32x4;

static __device__ __forceinline__ float leaky02(float v) {
  return v > 0.0f ? v : 0.2f * v;
}

// fp32 -> bf16 (round to nearest even), stored as ushort
static __device__ __forceinline__ ushort f2bf(float f) {
  uint b = __float_as_uint(f);
  return (ushort)((b + 0x7fffu + ((b >> 16) & 1u)) >> 16);
}
static __device__ __forceinline__ float bf2f(ushort u) {
  return __uint_as_float(((uint)u) << 16);
}

static __device__ __forceinline__ float selu_f(float y) {
  return y > 0.f ? SELU_SCALE * y : SELU_SCALE * SELU_ALPHA * (__expf(y) - 1.f);
}

// ---------------- W pack: W[128][128] f32 row-major -> MFMA A-fragment order (bf16) ------
// flat t = (((ct*4+kt)*4+g)*16+i)*8+b  -> bits: b[0:2], i[3:6], g[7:8], kt[9:10], ct[11:13]
// Wp[t] = bf16( W[(kt*32+g*8+b)*128 + ct*16+i] )
__global__ __launch_bounds__(256) void pack_kernel(const float* __restrict__ W1,
                                                   const float* __restrict__ W2,
                                                   ushort* __restrict__ Wp1,
                                                   ushort* __restrict__ Wp2) {
  int idx = blockIdx.x * 256 + threadIdx.x;  // 0..32767
  const float* W = (idx < 16384) ? W1 : W2;
  ushort* Wp = (idx < 16384) ? Wp1 : Wp2;
  int t = idx & 16383;
  int b = t & 7, i = (t >> 3) & 15, g = (t >> 7) & 3, kt = (t >> 9) & 3, ct = t >> 11;
  int k = kt * 32 + g * 8 + b, col = ct * 16 + i;
  Wp[t] = f2bf(W[k * 128 + col]);
}

// ---------------- MFMA GEMM + fused scores (+ optional fused BN+SELU on X load) ---------
// Y[n,128](bf16) = act(X[n,128] f32) @ W ; ssrc/sdst from f32 accumulators.
// Lane l: row = row0 + (l&15); acc[ct][r] = Y[row][ct*16 + (l>>4)*4 + r].
template <int HEADS, bool BN>
__global__ __launch_bounds__(256) void gemm_mfma_kernel(
    const float* __restrict__ X, const ushort* __restrict__ Wp, ushort* __restrict__ H,
    const float* __restrict__ asr, const float* __restrict__ adt,
    float* __restrict__ ssrc, float* __restrict__ sdst, int n,
    const float* __restrict__ stats, const float* __restrict__ gamma,
    const float* __restrict__ beta) {
  __shared__ float sc[128], sh[128];
  if (BN) {
    int t = threadIdx.x;
    if (t < 128) {
      float invN = 1.0f / (float)n;
      float mu = stats[t] * invN;
      float var = stats[128 + t] * invN - mu * mu;
      float rs = rsqrtf(var + 1e-5f);
      float s = gamma[t] * rs;
      sc[t] = s;
      sh[t] = beta[t] - s * mu;
    }
    __syncthreads();
  }
  const int tid = threadIdx.x;
  const int w = tid >> 6, l = tid & 63;
  const int lj = l & 15, lg = l >> 4;
  const int row = blockIdx.x * 64 + w * 16 + lj;
  const bool rowok = row < n;
  const float* xrow = X + (size_t)row * 128;

  f32x4 acc[8];
#pragma unroll
  for (int ct = 0; ct < 8; ++ct) acc[ct] = (f32x4){0.f, 0.f, 0.f, 0.f};

#pragma unroll
  for (int kt = 0; kt < 4; ++kt) {
    const int k0 = kt * 32 + lg * 8;
    float4 xa = make_float4(0.f, 0.f, 0.f, 0.f), xb = xa;
    if (rowok) {
      xa = *(const float4*)(xrow + k0);
      xb = *(const float4*)(xrow + k0 + 4);
    }
    float xv[8] = {xa.x, xa.y, xa.z, xa.w, xb.x, xb.y, xb.z, xb.w};
    if (BN) {
#pragma unroll
      for (int b = 0; b < 8; ++b) xv[b] = selu_f(xv[b] * sc[k0 + b] + sh[k0 + b]);
    }
    short8 bx;
#pragma unroll
    for (int b = 0; b < 8; ++b) bx[b] = (short)f2bf(xv[b]);
#pragma unroll
    for (int ct = 0; ct < 8; ++ct) {
      short8 af = *(const short8*)(Wp + ((((ct * 4 + kt) * 4 + lg) * 16 + lj) << 3));
      acc[ct] = __builtin_amdgcn_mfma_f32_16x16x32_bf16(af, bx, acc[ct], 0, 0, 0);
    }
  }

  // ---- H store: per ct, 4 consecutive bf16 cols ----
  if (rowok) {
#pragma unroll
    for (int ct = 0; ct < 8; ++ct) {
      ushort4 h4;
      h4.x = f2bf(acc[ct][0]);
      h4.y = f2bf(acc[ct][1]);
      h4.z = f2bf(acc[ct][2]);
      h4.w = f2bf(acc[ct][3]);
      *(ushort4*)&H[(size_t)row * 128 + ct * 16 + lg * 4] = h4;
    }
  }

  // ---- fused attention scores ----
  if (HEADS == 8) {
    float ps[8], pd[8];
#pragma unroll
    for (int ct = 0; ct < 8; ++ct) {
      float4 av = *(const float4*)&asr[ct * 16 + lg * 4];
      float4 dv = *(const float4*)&adt[ct * 16 + lg * 4];
      ps[ct] = acc[ct][0] * av.x + acc[ct][1] * av.y + acc[ct][2] * av.z + acc[ct][3] * av.w;
      pd[ct] = acc[ct][0] * dv.x + acc[ct][1] * dv.y + acc[ct][2] * dv.z + acc[ct][3] * dv.w;
      ps[ct] += __shfl_xor(ps[ct], 16);
      ps[ct] += __shfl_xor(ps[ct], 32);
      pd[ct] += __shfl_xor(pd[ct], 16);
      pd[ct] += __shfl_xor(pd[ct], 32);
    }
    if (lg == 0 && rowok) {
      *(float4*)&ssrc[(size_t)row * 8] = make_float4(ps[0], ps[1], ps[2], ps[3]);
      *(float4*)&ssrc[(size_t)row * 8 + 4] = make_float4(ps[4], ps[5], ps[6], ps[7]);
      *(float4*)&sdst[(size_t)row * 8] = make_float4(pd[0], pd[1], pd[2], pd[3]);
      *(float4*)&sdst[(size_t)row * 8 + 4] = make_float4(pd[4], pd[5], pd[6], pd[7]);
    }
  } else {
    float ps = 0.f, pd = 0.f;
#pragma unroll
    for (int ct = 0; ct < 8; ++ct) {
      float4 av = *(const float4*)&asr[ct * 16 + lg * 4];
      float4 dv = *(const float4*)&adt[ct * 16 + lg * 4];
      ps += acc[ct][0] * av.x + acc[ct][1] * av.y + acc[ct][2] * av.z + acc[ct][3] * av.w;
      pd += acc[ct][0] * dv.x + acc[ct][1] * dv.y + acc[ct][2] * dv.z + acc[ct][3] * dv.w;
    }
    ps += __shfl_xor(ps, 16);
    ps += __shfl_xor(ps, 32);
    pd += __shfl_xor(pd, 16);
    pd += __shfl_xor(pd, 32);
    if (lg == 0 && rowok) {
      ssrc[row] = ps;
      sdst[row] = pd;
    }
  }
}

// ---------------- CSR build ----------------
__global__ void hist_kernel(const int* __restrict__ ei, int* __restrict__ deg, int nE, int nN) {
  int e = blockIdx.x * blockDim.x + threadIdx.x;
  if (e >= nE + nN) return;
  int dst = (e < nE) ? ei[nE + e] : (e - nE);
  atomicAdd(&deg[dst], 1);
}

__global__ __launch_bounds__(256) void scan1_kernel(const int* __restrict__ deg,
                                                    int* __restrict__ bsum, int n) {
  __shared__ int red[4];
  int b = blockIdx.x, tid = threadIdx.x;
  int lane = tid & 63, w = tid >> 6;
  int base = b * 1024 + tid * 4;
  int s = 0;
#pragma unroll
  for (int j = 0; j < 4; ++j) {
    int idx = base + j;
    if (idx < n) s += deg[idx];
  }
#pragma unroll
  for (int sh = 1; sh < 64; sh <<= 1) s += __shfl_xor(s, sh);
  if (lane == 0) red[w] = s;
  __syncthreads();
  if (tid == 0) bsum[b] = red[0] + red[1] + red[2] + red[3];
}

__global__ __launch_bounds__(64) void scan2_kernel(int* __restrict__ bsum, int* __restrict__ offs,
                                                   int nb, int n) {
  int lane = threadIdx.x;
  int carry = 0;
  for (int base = 0; base < nb; base += 64) {
    int v = (base + lane < nb) ? bsum[base + lane] : 0;
    int x = v;
#pragma unroll
    for (int s = 1; s < 64; s <<= 1) {
      int t = __shfl_up(x, s);
      if (lane >= s) x += t;
    }
    if (base + lane < nb) bsum[base + lane] = carry + x - v;  // exclusive
    carry += __shfl(x, 63);
  }
  if (lane == 0) offs[n] = carry;
}

__global__ __launch_bounds__(256) void scan3_kernel(const int* __restrict__ deg,
                                                    const int* __restrict__ bsum,
                                                    int* __restrict__ offs, int n) {
  __shared__ int wsum[4];
  int b = blockIdx.x, tid = threadIdx.x;
  int lane = tid & 63, w = tid >> 6;
  int base = b * 1024 + tid * 4;
  int v[4];
  int t = 0;
#pragma unroll
  for (int j = 0; j < 4; ++j) {
    int idx = base + j;
    v[j] = (idx < n) ? deg[idx] : 0;
    t += v[j];
  }
  int x = t;
#pragma unroll
  for (int s = 1; s < 64; s <<= 1) {
    int tt = __shfl_up(x, s);
    if (lane >= s) x += tt;
  }
  if (lane == 63) wsum[w] = x;
  __syncthreads();
  int woff = 0;
#pragma unroll
  for (int ww = 0; ww < 4; ++ww)
    if (ww < w) woff += wsum[ww];
  int off = bsum[b] + woff + x - t;
#pragma unroll
  for (int j = 0; j < 4; ++j) {
    int idx = base + j;
    if (idx < n) offs[idx] = off;
    off += v[j];
  }
}

__global__ void fill_kernel(const int* __restrict__ ei, const int* __restrict__ offs,
                            int* __restrict__ cursor, int* __restrict__ csr, int nE, int nN) {
  int e = blockIdx.x * blockDim.x + threadIdx.x;
  if (e >= nE + nN) return;
  int src, dst;
  if (e < nE) {
    src = ei[e];
    dst = ei[nE + e];
  } else {
    src = dst = e - nE;
  }
  int pos = atomicAdd(&cursor[dst], 1);
  csr[offs[dst] + pos] = src;
}

// ---------------- aggregation (fused softmax): TWO dst nodes per wave ----------------
// Half-wave (32 lanes) per node; each lane owns 4 consecutive channels (ushort4 loads).
// Branchless guards: expired lanes use s=0 (valid address) with alpha=0.
__global__ __launch_bounds__(256) void agg1_kernel(const ushort* __restrict__ h1,
                                                   const int* __restrict__ csr,
                                                   const int* __restrict__ offs,
                                                   const float* __restrict__ ssrc,
                                                   const float* __restrict__ sdst,
                                                   const float* __restrict__ bias,
                                                   float* __restrict__ out, int nN) {
  int gw = (blockIdx.x * blockDim.x + threadIdx.x) >> 6;  // wave id
  int lane = threadIdx.x & 63;
  int half = lane >> 5, ll = lane & 31;
  int node = gw * 2 + half;
  bool ok = node < nN;
  int c = ll * 4;     // 4 channels per lane
  int h = ll >> 2;    // head = channel/16
  float sd = ok ? sdst[node * 8 + h] : 0.f;
  int beg = ok ? offs[node] : 0;
  int deg = ok ? offs[node + 1] - beg : 0;
  int dmax = max(deg, __shfl_xor(deg, 32));
  float a0 = 0.f, a1 = 0.f, a2 = 0.f, a3 = 0.f, den = 0.f;
  int i = 0;
  for (; i + 1 < dmax; i += 2) {
    bool vA = i < deg, vB = i + 1 < deg;
    int sA = vA ? csr[beg + i] : 0;
    int sB = vB ? csr[beg + i + 1] : 0;
    float eA = ssrc[sA * 8 + h];
    float eB = ssrc[sB * 8 + h];
    ushort4 uA = *(const ushort4*)&h1[(size_t)sA * 128 + c];
    ushort4 uB = *(const ushort4*)&h1[(size_t)sB * 128 + c];
    float aA = vA ? __expf(leaky02(eA + sd)) : 0.f;
    float aB = vB ? __expf(leaky02(eB + sd)) : 0.f;
    a0 += aA * bf2f(uA.x) + aB * bf2f(uB.x);
    a1 += aA * bf2f(uA.y) + aB * bf2f(uB.y);
    a2 += aA * bf2f(uA.z) + aB * bf2f(uB.z);
    a3 += aA * bf2f(uA.w) + aB * bf2f(uB.w);
    den += aA + aB;
  }
  if (i < dmax) {
    bool vA = i < deg;
    int sA = vA ? csr[beg + i] : 0;
    float eA = ssrc[sA * 8 + h];
    ushort4 uA = *(const ushort4*)&h1[(size_t)sA * 128 + c];
    float aA = vA ? __expf(leaky02(eA + sd)) : 0.f;
    a0 += aA * bf2f(uA.x);
    a1 += aA * bf2f(uA.y);
    a2 += aA * bf2f(uA.z);
    a3 += aA * bf2f(uA.w);
    den += aA;
  }
  if (ok) {
    float invd = 1.0f / (den + 1e-16f);
    float4 bv = *(const float4*)&bias[c];
    *(float4*)&out[(size_t)node * 128 + c] =
        make_float4(a0 * invd + bv.x, a1 * invd + bv.y, a2 * invd + bv.z, a3 * invd + bv.w);
  }
}

__global__ __launch_bounds__(256) void agg2_kernel(const ushort* __restrict__ h2,
                                                   const int* __restrict__ csr,
                                                   const int* __restrict__ offs,
                                                   const float* __restrict__ ssrc,
                                                   const float* __restrict__ sdst,
                                                   const float* __restrict__ bias,
                                                   float* __restrict__ out, int nN) {
  int gw = (blockIdx.x * blockDim.x + threadIdx.x) >> 6;
  int lane = threadIdx.x & 63;
  int half = lane >> 5, ll = lane & 31;
  int node = gw * 2 + half;
  bool ok = node < nN;
  int c = ll * 4;
  float sd = ok ? sdst[node] : 0.f;
  int beg = ok ? offs[node] : 0;
  int deg = ok ? offs[node + 1] - beg : 0;
  int dmax = max(deg, __shfl_xor(deg, 32));
  float a0 = 0.f, a1 = 0.f, a2 = 0.f, a3 = 0.f, den = 0.f;
  int i = 0;
  for (; i + 1 < dmax; i += 2) {
    bool vA = i < deg, vB = i + 1 < deg;
    int sA = vA ? csr[beg + i] : 0;
    int sB = vB ? csr[beg + i + 1] : 0;
    float eA = ssrc[sA];
    float eB = ssrc[sB];
    ushort4 uA = *(const ushort4*)&h2[(size_t)sA * 128 + c];
    ushort4 uB = *(const ushort4*)&h2[(size_t)sB * 128 + c];
    float aA = vA ? __expf(leaky02(eA + sd)) : 0.f;
    float aB = vB ? __expf(leaky02(eB + sd)) : 0.f;
    a0 += aA * bf2f(uA.x) + aB * bf2f(uB.x);
    a1 += aA * bf2f(uA.y) + aB * bf2f(uB.y);
    a2 += aA * bf2f(uA.z) + aB * bf2f(uB.z);
    a3 += aA * bf2f(uA.w) + aB * bf2f(uB.w);
    den += aA + aB;
  }
  if (i < dmax) {
    bool vA = i < deg;
    int sA = vA ? csr[beg + i] : 0;
    float eA = ssrc[sA];
    ushort4 uA = *(const ushort4*)&h2[(size_t)sA * 128 + c];
    float aA = vA ? __expf(leaky02(eA + sd)) : 0.f;
    a0 += aA * bf2f(uA.x);
    a1 += aA * bf2f(uA.y);
    a2 += aA * bf2f(uA.z);
    a3 += aA * bf2f(uA.w);
    den += aA;
  }
  if (ok) {
    float invd = 1.0f / (den + 1e-16f);
    float4 bv = *(const float4*)&bias[c];
    *(float4*)&out[(size_t)node * 128 + c] =
        make_float4(a0 * invd + bv.x, a1 * invd + bv.y, a2 * invd + bv.z, a3 * invd + bv.w);
  }
}

// ---------------- column stats (sum, sumsq) for BatchNorm: 64 rows/block ----------------
__global__ __launch_bounds__(256) void stats_kernel(const float* __restrict__ X,
                                                    float* __restrict__ stats, int n) {
  __shared__ float red[256];
  int tid = threadIdx.x;
  int c = tid & 127;
  int half = tid >> 7;
  float s = 0.f, sq = 0.f;
  int rbeg = (int)blockIdx.x * 64 + half;
  int rend = min((int)(blockIdx.x + 1) * 64, n);
#pragma unroll 4
  for (int r = rbeg; r < rend; r += 2) {
    float v = X[(size_t)r * 128 + c];
    s += v;
    sq += v * v;
  }
  red[tid] = s;
  __syncthreads();
  float s2 = (half == 0) ? s + red[tid + 128] : 0.f;
  __syncthreads();
  red[tid] = sq;
  __syncthreads();
  if (half == 0) {
    float sq2 = sq + red[tid + 128];
    atomicAdd(&stats[c], s2);
    atomicAdd(&stats[128 + c], sq2);
  }
}

// ---------------- BatchNorm (batch stats, biased var) + SELU ----------------
__global__ __launch_bounds__(256) void bnselu_kernel(const float* __restrict__ X,
                                                     const float* __restrict__ stats,
                                                     const float* __restrict__ gamma,
                                                     const float* __restrict__ beta,
                                                     float* __restrict__ Y, int n) {
  int gid = blockIdx.x * blockDim.x + threadIdx.x;
  if (gid >= n * 32) return;
  int c = (gid & 31) * 4;
  int r = gid >> 5;
  float invN = 1.0f / (float)n;
  float4 x = *(const float4*)&X[(size_t)r * 128 + c];
  float o[4];
#pragma unroll
  for (int j = 0; j < 4; ++j) {
    float xx = (j == 0) ? x.x : (j == 1) ? x.y : (j == 2) ? x.z : x.w;
    float mu = stats[c + j] * invN;
    float var = stats[128 + c + j] * invN - mu * mu;
    float rs = rsqrtf(var + 1e-5f);
    float y = gamma[c + j] * ((xx - mu) * rs) + beta[c + j];
    o[j] = selu_f(y);
  }
  *(float4*)&Y[(size_t)r * 128 + c] = make_float4(o[0], o[1], o[2], o[3]);
}

extern "C" void kernel_launch(void* const* d_in, const int* in_sizes, int n_in,
                              void* d_out, int out_size, void* d_ws, size_t ws_size,
                              hipStream_t stream) {
  const float* x   = (const float*)d_in[0];
  const int*   ei  = (const int*)d_in[1];
  // d_in[2] = edge_attr: unused (edge_dim=None)
  const float* W1  = (const float*)d_in[3];
  const float* as1 = (const float*)d_in[4];
  const float* ad1 = (const float*)d_in[5];
  const float* b1  = (const float*)d_in[6];
  const float* g1  = (const float*)d_in[7];
  const float* be1 = (const float*)d_in[8];
  const float* W2  = (const float*)d_in[9];
  const float* as2 = (const float*)d_in[10];
  const float* ad2 = (const float*)d_in[11];
  const float* b2  = (const float*)d_in[12];
  const float* g2  = (const float*)d_in[13];
  const float* be2 = (const float*)d_in[14];
  float* out = (float*)d_out;

  const int n  = in_sizes[0] / 128;   // 50000
  const int nE = in_sizes[1] / 2;     // 800000
  const int EA = nE + n;              // 850000
  const int nb = (n + 1023) / 1024;   // scan chunks

  float* ws = (float*)d_ws;
  size_t o = 0;
  float* Bf = ws + o;     o += (size_t)n * 128;   // fp32: agg output / BN input
  ushort* H = (ushort*)(ws + o); o += (size_t)n * 64;  // bf16 h (gather table, reused)
  float* ssrc1 = ws + o;  o += (size_t)n * 8;
  float* sdst1 = ws + o;  o += (size_t)n * 8;
  float* ssrc2 = ws + o;  o += n;
  float* sdst2 = ws + o;  o += n;
  ushort* Wp1 = (ushort*)(ws + o); o += 8192;     // 16384 bf16
  ushort* Wp2 = (ushort*)(ws + o); o += 8192;
  // ---- zero region start ----
  float* zbase = ws + o;
  float* stats1 = ws + o; o += 256;
  float* stats2 = ws + o; o += 256;
  int* deg    = (int*)(ws + o); o += n;
  int* cursor = (int*)(ws + o); o += n;
  size_t zwords = (size_t)((ws + o) - zbase);
  // ---- zero region end ----
  int* offs = (int*)(ws + o); o += (size_t)n + 1;
  int* csr  = (int*)(ws + o); o += EA;
  int* bsum = (int*)(ws + o); o += nb;

  hipMemsetAsync(zbase, 0, zwords * sizeof(float), stream);

  // CSR build (shared by both layers) + weight pack
  hist_kernel<<<(EA + 255) / 256, 256, 0, stream>>>(ei, deg, nE, n);
  scan1_kernel<<<nb, 256, 0, stream>>>(deg, bsum, n);
  scan2_kernel<<<1, 64, 0, stream>>>(bsum, offs, nb, n);
  scan3_kernel<<<nb, 256, 0, stream>>>(deg, bsum, offs, n);
  fill_kernel<<<(EA + 255) / 256, 256, 0, stream>>>(ei, offs, cursor, csr, nE, n);
  pack_kernel<<<128, 256, 0, stream>>>(W1, W2, Wp1, Wp2);

  // ---- layer 1 (GEMM + fused scores) ----
  gemm_mfma_kernel<8, false><<<(n + 63) / 64, 256, 0, stream>>>(
      x, Wp1, H, as1, ad1, ssrc1, sdst1, n, nullptr, nullptr, nullptr);
  agg1_kernel<<<(n + 7) / 8, 256, 0, stream>>>(H, csr, offs, ssrc1, sdst1, b1, Bf, n);
  stats_kernel<<<(n + 63) / 64, 256, 0, stream>>>(Bf, stats1, n);

  // ---- layer 2 (BN+SELU fused into GEMM2 X load; GEMM + fused scores) ----
  gemm_mfma_kernel<1, true><<<(n + 63) / 64, 256, 0, stream>>>(
      Bf, Wp2, H, as2, ad2, ssrc2, sdst2, n, stats1, g1, be1);
  agg2_kernel<<<(n + 7) / 8, 256, 0, stream>>>(H, csr, offs, ssrc2, sdst2, b2, out, n);
  stats_kernel<<<(n + 63) / 64, 256, 0, stream>>>(out, stats2, n);
  bnselu_kernel<<<(n * 32 + 255) / 256, 256, 0, stream>>>(out, stats2, g2, be2, out, n);
}

// Round 7
// 286.471 us; speedup vs baseline: 1.0795x; 1.0795x over previous
//
#include <hip/hip_runtime.h>

#define SELU_SCALE 1.0507009873554805f
#define SELU_ALPHA 1.6732632423543772f

typedef __attribute__((ext_vector_type(8))) short short8;
typedef __attribute__((ext_vector_type(4))) float f32x4;

static __device__ __forceinline__ float leaky02(float v) {
  return v > 0.0f ? v : 0.2f * v;
}

// fp32 -> bf16 (round to nearest even), stored as ushort
static __device__ __forceinline__ ushort f2bf(float f) {
  uint b = __float_as_uint(f);
  return (ushort)((b + 0x7fffu + ((b >> 16) & 1u)) >> 16);
}
static __device__ __forceinline__ float bf2f(ushort u) {
  return __uint_as_float(((uint)u) << 16);
}

static __device__ __forceinline__ float selu_f(float y) {
  return y > 0.f ? SELU_SCALE * y : SELU_SCALE * SELU_ALPHA * (__expf(y) - 1.f);
}

// ---------------- W pack: W[128][128] f32 row-major -> MFMA A-fragment order (bf16) ------
// flat t = (((ct*4+kt)*4+g)*16+i)*8+b  -> bits: b[0:2], i[3:6], g[7:8], kt[9:10], ct[11:13]
// Wp[t] = bf16( W[(kt*32+g*8+b)*128 + ct*16+i] )
__global__ __launch_bounds__(256) void pack_kernel(const float* __restrict__ W1,
                                                   const float* __restrict__ W2,
                                                   ushort* __restrict__ Wp1,
                                                   ushort* __restrict__ Wp2) {
  int idx = blockIdx.x * 256 + threadIdx.x;  // 0..32767
  const float* W = (idx < 16384) ? W1 : W2;
  ushort* Wp = (idx < 16384) ? Wp1 : Wp2;
  int t = idx & 16383;
  int b = t & 7, i = (t >> 3) & 15, g = (t >> 7) & 3, kt = (t >> 9) & 3, ct = t >> 11;
  int k = kt * 32 + g * 8 + b, col = ct * 16 + i;
  Wp[t] = f2bf(W[k * 128 + col]);
}

// ---------------- MFMA GEMM + fused scores (+ optional fused BN+SELU on X load) ---------
// Y[n,128](bf16) = act(X[n,128] f32) @ W ; ssrc/sdst from f32 accumulators.
// Lane l: row = row0 + (l&15); acc[ct][r] = Y[row][ct*16 + (l>>4)*4 + r].
template <int HEADS, bool BN>
__global__ __launch_bounds__(256) void gemm_mfma_kernel(
    const float* __restrict__ X, const ushort* __restrict__ Wp, ushort* __restrict__ H,
    const float* __restrict__ asr, const float* __restrict__ adt,
    float* __restrict__ ssrc, float* __restrict__ sdst, int n,
    const float* __restrict__ stats, const float* __restrict__ gamma,
    const float* __restrict__ beta) {
  __shared__ float sc[128], sh[128];
  if (BN) {
    int t = threadIdx.x;
    if (t < 128) {
      float invN = 1.0f / (float)n;
      float mu = stats[t] * invN;
      float var = stats[128 + t] * invN - mu * mu;
      float rs = rsqrtf(var + 1e-5f);
      float s = gamma[t] * rs;
      sc[t] = s;
      sh[t] = beta[t] - s * mu;
    }
    __syncthreads();
  }
  const int tid = threadIdx.x;
  const int w = tid >> 6, l = tid & 63;
  const int lj = l & 15, lg = l >> 4;
  const int row = blockIdx.x * 64 + w * 16 + lj;
  const bool rowok = row < n;
  const float* xrow = X + (size_t)row * 128;

  f32x4 acc[8];
#pragma unroll
  for (int ct = 0; ct < 8; ++ct) acc[ct] = (f32x4){0.f, 0.f, 0.f, 0.f};

#pragma unroll
  for (int kt = 0; kt < 4; ++kt) {
    const int k0 = kt * 32 + lg * 8;
    float4 xa = make_float4(0.f, 0.f, 0.f, 0.f), xb = xa;
    if (rowok) {
      xa = *(const float4*)(xrow + k0);
      xb = *(const float4*)(xrow + k0 + 4);
    }
    float xv[8] = {xa.x, xa.y, xa.z, xa.w, xb.x, xb.y, xb.z, xb.w};
    if (BN) {
#pragma unroll
      for (int b = 0; b < 8; ++b) xv[b] = selu_f(xv[b] * sc[k0 + b] + sh[k0 + b]);
    }
    short8 bx;
#pragma unroll
    for (int b = 0; b < 8; ++b) bx[b] = (short)f2bf(xv[b]);
#pragma unroll
    for (int ct = 0; ct < 8; ++ct) {
      short8 af = *(const short8*)(Wp + ((((ct * 4 + kt) * 4 + lg) * 16 + lj) << 3));
      acc[ct] = __builtin_amdgcn_mfma_f32_16x16x32_bf16(af, bx, acc[ct], 0, 0, 0);
    }
  }

  // ---- H store: per ct, 4 consecutive bf16 cols ----
  if (rowok) {
#pragma unroll
    for (int ct = 0; ct < 8; ++ct) {
      ushort4 h4;
      h4.x = f2bf(acc[ct][0]);
      h4.y = f2bf(acc[ct][1]);
      h4.z = f2bf(acc[ct][2]);
      h4.w = f2bf(acc[ct][3]);
      *(ushort4*)&H[(size_t)row * 128 + ct * 16 + lg * 4] = h4;
    }
  }

  // ---- fused attention scores ----
  if (HEADS == 8) {
    float ps[8], pd[8];
#pragma unroll
    for (int ct = 0; ct < 8; ++ct) {
      float4 av = *(const float4*)&asr[ct * 16 + lg * 4];
      float4 dv = *(const float4*)&adt[ct * 16 + lg * 4];
      ps[ct] = acc[ct][0] * av.x + acc[ct][1] * av.y + acc[ct][2] * av.z + acc[ct][3] * av.w;
      pd[ct] = acc[ct][0] * dv.x + acc[ct][1] * dv.y + acc[ct][2] * dv.z + acc[ct][3] * dv.w;
      ps[ct] += __shfl_xor(ps[ct], 16);
      ps[ct] += __shfl_xor(ps[ct], 32);
      pd[ct] += __shfl_xor(pd[ct], 16);
      pd[ct] += __shfl_xor(pd[ct], 32);
    }
    if (lg == 0 && rowok) {
      *(float4*)&ssrc[(size_t)row * 8] = make_float4(ps[0], ps[1], ps[2], ps[3]);
      *(float4*)&ssrc[(size_t)row * 8 + 4] = make_float4(ps[4], ps[5], ps[6], ps[7]);
      *(float4*)&sdst[(size_t)row * 8] = make_float4(pd[0], pd[1], pd[2], pd[3]);
      *(float4*)&sdst[(size_t)row * 8 + 4] = make_float4(pd[4], pd[5], pd[6], pd[7]);
    }
  } else {
    float ps = 0.f, pd = 0.f;
#pragma unroll
    for (int ct = 0; ct < 8; ++ct) {
      float4 av = *(const float4*)&asr[ct * 16 + lg * 4];
      float4 dv = *(const float4*)&adt[ct * 16 + lg * 4];
      ps += acc[ct][0] * av.x + acc[ct][1] * av.y + acc[ct][2] * av.z + acc[ct][3] * av.w;
      pd += acc[ct][0] * dv.x + acc[ct][1] * dv.y + acc[ct][2] * dv.z + acc[ct][3] * dv.w;
    }
    ps += __shfl_xor(ps, 16);
    ps += __shfl_xor(ps, 32);
    pd += __shfl_xor(pd, 16);
    pd += __shfl_xor(pd, 32);
    if (lg == 0 && rowok) {
      ssrc[row] = ps;
      sdst[row] = pd;
    }
  }
}

// ---------------- CSR build ----------------
__global__ void hist_kernel(const int* __restrict__ ei, int* __restrict__ deg, int nE, int nN) {
  int e = blockIdx.x * blockDim.x + threadIdx.x;
  if (e >= nE + nN) return;
  int dst = (e < nE) ? ei[nE + e] : (e - nE);
  atomicAdd(&deg[dst], 1);
}

__global__ __launch_bounds__(256) void scan1_kernel(const int* __restrict__ deg,
                                                    int* __restrict__ bsum, int n) {
  __shared__ int red[4];
  int b = blockIdx.x, tid = threadIdx.x;
  int lane = tid & 63, w = tid >> 6;
  int base = b * 1024 + tid * 4;
  int s = 0;
#pragma unroll
  for (int j = 0; j < 4; ++j) {
    int idx = base + j;
    if (idx < n) s += deg[idx];
  }
#pragma unroll
  for (int sh = 1; sh < 64; sh <<= 1) s += __shfl_xor(s, sh);
  if (lane == 0) red[w] = s;
  __syncthreads();
  if (tid == 0) bsum[b] = red[0] + red[1] + red[2] + red[3];
}

__global__ __launch_bounds__(64) void scan2_kernel(int* __restrict__ bsum, int* __restrict__ offs,
                                                   int nb, int n) {
  int lane = threadIdx.x;
  int carry = 0;
  for (int base = 0; base < nb; base += 64) {
    int v = (base + lane < nb) ? bsum[base + lane] : 0;
    int x = v;
#pragma unroll
    for (int s = 1; s < 64; s <<= 1) {
      int t = __shfl_up(x, s);
      if (lane >= s) x += t;
    }
    if (base + lane < nb) bsum[base + lane] = carry + x - v;  // exclusive
    carry += __shfl(x, 63);
  }
  if (lane == 0) offs[n] = carry;
}

__global__ __launch_bounds__(256) void scan3_kernel(const int* __restrict__ deg,
                                                    const int* __restrict__ bsum,
                                                    int* __restrict__ offs, int n) {
  __shared__ int wsum[4];
  int b = blockIdx.x, tid = threadIdx.x;
  int lane = tid & 63, w = tid >> 6;
  int base = b * 1024 + tid * 4;
  int v[4];
  int t = 0;
#pragma unroll
  for (int j = 0; j < 4; ++j) {
    int idx = base + j;
    v[j] = (idx < n) ? deg[idx] : 0;
    t += v[j];
  }
  int x = t;
#pragma unroll
  for (int s = 1; s < 64; s <<= 1) {
    int tt = __shfl_up(x, s);
    if (lane >= s) x += tt;
  }
  if (lane == 63) wsum[w] = x;
  __syncthreads();
  int woff = 0;
#pragma unroll
  for (int ww = 0; ww < 4; ++ww)
    if (ww < w) woff += wsum[ww];
  int off = bsum[b] + woff + x - t;
#pragma unroll
  for (int j = 0; j < 4; ++j) {
    int idx = base + j;
    if (idx < n) offs[idx] = off;
    off += v[j];
  }
}

__global__ void fill_kernel(const int* __restrict__ ei, const int* __restrict__ offs,
                            int* __restrict__ cursor, int* __restrict__ csr, int nE, int nN) {
  int e = blockIdx.x * blockDim.x + threadIdx.x;
  if (e >= nE + nN) return;
  int src, dst;
  if (e < nE) {
    src = ei[e];
    dst = ei[nE + e];
  } else {
    src = dst = e - nE;
  }
  int pos = atomicAdd(&cursor[dst], 1);
  csr[offs[dst] + pos] = src;
}

// ---------------- aggregation (fused softmax): one node per wave, even/odd halves -------
// Half-wave 0 takes edges i=0,2,4,..; half 1 takes i=1,3,5,..; lane owns 4 channels
// (ushort4). Unroll 4 -> 4 independent gather chains per lane, 8 edges/wave/iter.
// Cross-half shfl_xor(32) reduce at the end; half 0 writes.
__global__ __launch_bounds__(256) void agg1_kernel(const ushort* __restrict__ h1,
                                                   const int* __restrict__ csr,
                                                   const int* __restrict__ offs,
                                                   const float* __restrict__ ssrc,
                                                   const float* __restrict__ sdst,
                                                   const float* __restrict__ bias,
                                                   float* __restrict__ out, int nN) {
  int wid = (blockIdx.x * blockDim.x + threadIdx.x) >> 6;  // node
  int lane = threadIdx.x & 63;
  int half = lane >> 5, ll = lane & 31;
  if (wid >= nN) return;
  int c = ll * 4;   // 4 channels per lane
  int h = ll >> 2;  // head = c/16
  float sd = sdst[wid * 8 + h];
  int beg = offs[wid];
  int deg = offs[wid + 1] - beg;
  float a0 = 0.f, a1 = 0.f, a2 = 0.f, a3 = 0.f, den = 0.f;
  int i = half;
  for (; i + 6 < deg; i += 8) {
    int s0 = csr[beg + i];
    int s1 = csr[beg + i + 2];
    int s2 = csr[beg + i + 4];
    int s3 = csr[beg + i + 6];
    float e0 = ssrc[s0 * 8 + h];
    float e1 = ssrc[s1 * 8 + h];
    float e2 = ssrc[s2 * 8 + h];
    float e3 = ssrc[s3 * 8 + h];
    ushort4 u0 = *(const ushort4*)&h1[(size_t)s0 * 128 + c];
    ushort4 u1 = *(const ushort4*)&h1[(size_t)s1 * 128 + c];
    ushort4 u2 = *(const ushort4*)&h1[(size_t)s2 * 128 + c];
    ushort4 u3 = *(const ushort4*)&h1[(size_t)s3 * 128 + c];
    float A0 = __expf(leaky02(e0 + sd));
    float A1 = __expf(leaky02(e1 + sd));
    float A2 = __expf(leaky02(e2 + sd));
    float A3 = __expf(leaky02(e3 + sd));
    a0 += A0 * bf2f(u0.x) + A1 * bf2f(u1.x) + A2 * bf2f(u2.x) + A3 * bf2f(u3.x);
    a1 += A0 * bf2f(u0.y) + A1 * bf2f(u1.y) + A2 * bf2f(u2.y) + A3 * bf2f(u3.y);
    a2 += A0 * bf2f(u0.z) + A1 * bf2f(u1.z) + A2 * bf2f(u2.z) + A3 * bf2f(u3.z);
    a3 += A0 * bf2f(u0.w) + A1 * bf2f(u1.w) + A2 * bf2f(u2.w) + A3 * bf2f(u3.w);
    den += (A0 + A1) + (A2 + A3);
  }
  for (; i < deg; i += 2) {
    int s0 = csr[beg + i];
    float e0 = ssrc[s0 * 8 + h];
    ushort4 u0 = *(const ushort4*)&h1[(size_t)s0 * 128 + c];
    float A0 = __expf(leaky02(e0 + sd));
    a0 += A0 * bf2f(u0.x);
    a1 += A0 * bf2f(u0.y);
    a2 += A0 * bf2f(u0.z);
    a3 += A0 * bf2f(u0.w);
    den += A0;
  }
  a0 += __shfl_xor(a0, 32);
  a1 += __shfl_xor(a1, 32);
  a2 += __shfl_xor(a2, 32);
  a3 += __shfl_xor(a3, 32);
  den += __shfl_xor(den, 32);
  if (half == 0) {
    float invd = 1.0f / (den + 1e-16f);
    float4 bv = *(const float4*)&bias[c];
    *(float4*)&out[(size_t)wid * 128 + c] =
        make_float4(a0 * invd + bv.x, a1 * invd + bv.y, a2 * invd + bv.z, a3 * invd + bv.w);
  }
}

__global__ __launch_bounds__(256) void agg2_kernel(const ushort* __restrict__ h2,
                                                   const int* __restrict__ csr,
                                                   const int* __restrict__ offs,
                                                   const float* __restrict__ ssrc,
                                                   const float* __restrict__ sdst,
                                                   const float* __restrict__ bias,
                                                   float* __restrict__ out, int nN) {
  int wid = (blockIdx.x * blockDim.x + threadIdx.x) >> 6;
  int lane = threadIdx.x & 63;
  int half = lane >> 5, ll = lane & 31;
  if (wid >= nN) return;
  int c = ll * 4;
  float sd = sdst[wid];
  int beg = offs[wid];
  int deg = offs[wid + 1] - beg;
  float a0 = 0.f, a1 = 0.f, a2 = 0.f, a3 = 0.f, den = 0.f;
  int i = half;
  for (; i + 6 < deg; i += 8) {
    int s0 = csr[beg + i];
    int s1 = csr[beg + i + 2];
    int s2 = csr[beg + i + 4];
    int s3 = csr[beg + i + 6];
    float e0 = ssrc[s0];
    float e1 = ssrc[s1];
    float e2 = ssrc[s2];
    float e3 = ssrc[s3];
    ushort4 u0 = *(const ushort4*)&h2[(size_t)s0 * 128 + c];
    ushort4 u1 = *(const ushort4*)&h2[(size_t)s1 * 128 + c];
    ushort4 u2 = *(const ushort4*)&h2[(size_t)s2 * 128 + c];
    ushort4 u3 = *(const ushort4*)&h2[(size_t)s3 * 128 + c];
    float A0 = __expf(leaky02(e0 + sd));
    float A1 = __expf(leaky02(e1 + sd));
    float A2 = __expf(leaky02(e2 + sd));
    float A3 = __expf(leaky02(e3 + sd));
    a0 += A0 * bf2f(u0.x) + A1 * bf2f(u1.x) + A2 * bf2f(u2.x) + A3 * bf2f(u3.x);
    a1 += A0 * bf2f(u0.y) + A1 * bf2f(u1.y) + A2 * bf2f(u2.y) + A3 * bf2f(u3.y);
    a2 += A0 * bf2f(u0.z) + A1 * bf2f(u1.z) + A2 * bf2f(u2.z) + A3 * bf2f(u3.z);
    a3 += A0 * bf2f(u0.w) + A1 * bf2f(u1.w) + A2 * bf2f(u2.w) + A3 * bf2f(u3.w);
    den += (A0 + A1) + (A2 + A3);
  }
  for (; i < deg; i += 2) {
    int s0 = csr[beg + i];
    float e0 = ssrc[s0];
    ushort4 u0 = *(const ushort4*)&h2[(size_t)s0 * 128 + c];
    float A0 = __expf(leaky02(e0 + sd));
    a0 += A0 * bf2f(u0.x);
    a1 += A0 * bf2f(u0.y);
    a2 += A0 * bf2f(u0.z);
    a3 += A0 * bf2f(u0.w);
    den += A0;
  }
  a0 += __shfl_xor(a0, 32);
  a1 += __shfl_xor(a1, 32);
  a2 += __shfl_xor(a2, 32);
  a3 += __shfl_xor(a3, 32);
  den += __shfl_xor(den, 32);
  if (half == 0) {
    float invd = 1.0f / (den + 1e-16f);
    float4 bv = *(const float4*)&bias[c];
    *(float4*)&out[(size_t)wid * 128 + c] =
        make_float4(a0 * invd + bv.x, a1 * invd + bv.y, a2 * invd + bv.z, a3 * invd + bv.w);
  }
}

// ---------------- column stats (sum, sumsq) for BatchNorm: 64 rows/block ----------------
__global__ __launch_bounds__(256) void stats_kernel(const float* __restrict__ X,
                                                    float* __restrict__ stats, int n) {
  __shared__ float red[256];
  int tid = threadIdx.x;
  int c = tid & 127;
  int half = tid >> 7;
  float s = 0.f, sq = 0.f;
  int rbeg = (int)blockIdx.x * 64 + half;
  int rend = min((int)(blockIdx.x + 1) * 64, n);
#pragma unroll 4
  for (int r = rbeg; r < rend; r += 2) {
    float v = X[(size_t)r * 128 + c];
    s += v;
    sq += v * v;
  }
  red[tid] = s;
  __syncthreads();
  float s2 = (half == 0) ? s + red[tid + 128] : 0.f;
  __syncthreads();
  red[tid] = sq;
  __syncthreads();
  if (half == 0) {
    float sq2 = sq + red[tid + 128];
    atomicAdd(&stats[c], s2);
    atomicAdd(&stats[128 + c], sq2);
  }
}

// ---------------- BatchNorm (batch stats, biased var) + SELU ----------------
__global__ __launch_bounds__(256) void bnselu_kernel(const float* __restrict__ X,
                                                     const float* __restrict__ stats,
                                                     const float* __restrict__ gamma,
                                                     const float* __restrict__ beta,
                                                     float* __restrict__ Y, int n) {
  int gid = blockIdx.x * blockDim.x + threadIdx.x;
  if (gid >= n * 32) return;
  int c = (gid & 31) * 4;
  int r = gid >> 5;
  float invN = 1.0f / (float)n;
  float4 x = *(const float4*)&X[(size_t)r * 128 + c];
  float o[4];
#pragma unroll
  for (int j = 0; j < 4; ++j) {
    float xx = (j == 0) ? x.x : (j == 1) ? x.y : (j == 2) ? x.z : x.w;
    float mu = stats[c + j] * invN;
    float var = stats[128 + c + j] * invN - mu * mu;
    float rs = rsqrtf(var + 1e-5f);
    float y = gamma[c + j] * ((xx - mu) * rs) + beta[c + j];
    o[j] = selu_f(y);
  }
  *(float4*)&Y[(size_t)r * 128 + c] = make_float4(o[0], o[1], o[2], o[3]);
}

extern "C" void kernel_launch(void* const* d_in, const int* in_sizes, int n_in,
                              void* d_out, int out_size, void* d_ws, size_t ws_size,
                              hipStream_t stream) {
  const float* x   = (const float*)d_in[0];
  const int*   ei  = (const int*)d_in[1];
  // d_in[2] = edge_attr: unused (edge_dim=None)
  const float* W1  = (const float*)d_in[3];
  const float* as1 = (const float*)d_in[4];
  const float* ad1 = (const float*)d_in[5];
  const float* b1  = (const float*)d_in[6];
  const float* g1  = (const float*)d_in[7];
  const float* be1 = (const float*)d_in[8];
  const float* W2  = (const float*)d_in[9];
  const float* as2 = (const float*)d_in[10];
  const float* ad2 = (const float*)d_in[11];
  const float* b2  = (const float*)d_in[12];
  const float* g2  = (const float*)d_in[13];
  const float* be2 = (const float*)d_in[14];
  float* out = (float*)d_out;

  const int n  = in_sizes[0] / 128;   // 50000
  const int nE = in_sizes[1] / 2;     // 800000
  const int EA = nE + n;              // 850000
  const int nb = (n + 1023) / 1024;   // scan chunks

  float* ws = (float*)d_ws;
  size_t o = 0;
  float* Bf = ws + o;     o += (size_t)n * 128;   // fp32: agg output / BN input
  ushort* H = (ushort*)(ws + o); o += (size_t)n * 64;  // bf16 h (gather table, reused)
  float* ssrc1 = ws + o;  o += (size_t)n * 8;
  float* sdst1 = ws + o;  o += (size_t)n * 8;
  float* ssrc2 = ws + o;  o += n;
  float* sdst2 = ws + o;  o += n;
  ushort* Wp1 = (ushort*)(ws + o); o += 8192;     // 16384 bf16
  ushort* Wp2 = (ushort*)(ws + o); o += 8192;
  // ---- zero region start ----
  float* zbase = ws + o;
  float* stats1 = ws + o; o += 256;
  float* stats2 = ws + o; o += 256;
  int* deg    = (int*)(ws + o); o += n;
  int* cursor = (int*)(ws + o); o += n;
  size_t zwords = (size_t)((ws + o) - zbase);
  // ---- zero region end ----
  int* offs = (int*)(ws + o); o += (size_t)n + 1;
  int* csr  = (int*)(ws + o); o += EA;
  int* bsum = (int*)(ws + o); o += nb;

  hipMemsetAsync(zbase, 0, zwords * sizeof(float), stream);

  // CSR build (shared by both layers) + weight pack
  hist_kernel<<<(EA + 255) / 256, 256, 0, stream>>>(ei, deg, nE, n);
  scan1_kernel<<<nb, 256, 0, stream>>>(deg, bsum, n);
  scan2_kernel<<<1, 64, 0, stream>>>(bsum, offs, nb, n);
  scan3_kernel<<<nb, 256, 0, stream>>>(deg, bsum, offs, n);
  fill_kernel<<<(EA + 255) / 256, 256, 0, stream>>>(ei, offs, cursor, csr, nE, n);
  pack_kernel<<<128, 256, 0, stream>>>(W1, W2, Wp1, Wp2);

  // ---- layer 1 (GEMM + fused scores) ----
  gemm_mfma_kernel<8, false><<<(n + 63) / 64, 256, 0, stream>>>(
      x, Wp1, H, as1, ad1, ssrc1, sdst1, n, nullptr, nullptr, nullptr);
  agg1_kernel<<<(n + 3) / 4, 256, 0, stream>>>(H, csr, offs, ssrc1, sdst1, b1, Bf, n);
  stats_kernel<<<(n + 63) / 64, 256, 0, stream>>>(Bf, stats1, n);

  // ---- layer 2 (BN+SELU fused into GEMM2 X load; GEMM + fused scores) ----
  gemm_mfma_kernel<1, true><<<(n + 63) / 64, 256, 0, stream>>>(
      Bf, Wp2, H, as2, ad2, ssrc2, sdst2, n, stats1, g1, be1);
  agg2_kernel<<<(n + 3) / 4, 256, 0, stream>>>(H, csr, offs, ssrc2, sdst2, b2, out, n);
  stats_kernel<<<(n + 63) / 64, 256, 0, stream>>>(out, stats2, n);
  bnselu_kernel<<<(n * 32 + 255) / 256, 256, 0, stream>>>(out, stats2, g2, be2, out, n);
}

// Round 8
// 233.304 us; speedup vs baseline: 1.3255x; 1.2279x over previous
//
#include <hip/hip_runtime.h>

#define SELU_SCALE 1.0507009873554805f
#define SELU_ALPHA 1.6732632423543772f

typedef __attribute__((ext_vector_type(8))) short short8;
typedef __attribute__((ext_vector_type(4))) float f32x4;

#define BCAP 20480  // bucket capacity (mean ~17408, deterministic inputs, +23 sigma)

static __device__ __forceinline__ float leaky02(float v) {
  return v > 0.0f ? v : 0.2f * v;
}

// fp32 -> bf16 (round to nearest even), stored as ushort
static __device__ __forceinline__ ushort f2bf(float f) {
  uint b = __float_as_uint(f);
  return (ushort)((b + 0x7fffu + ((b >> 16) & 1u)) >> 16);
}
static __device__ __forceinline__ float bf2f(ushort u) {
  return __uint_as_float(((uint)u) << 16);
}

static __device__ __forceinline__ float selu_f(float y) {
  return y > 0.f ? SELU_SCALE * y : SELU_SCALE * SELU_ALPHA * (__expf(y) - 1.f);
}

// ---------------- W pack: W[128][128] f32 row-major -> MFMA A-fragment order (bf16) ------
// flat t = (((ct*4+kt)*4+g)*16+i)*8+b  -> bits: b[0:2], i[3:6], g[7:8], kt[9:10], ct[11:13]
// Wp[t] = bf16( W[(kt*32+g*8+b)*128 + ct*16+i] )
__global__ __launch_bounds__(256) void pack_kernel(const float* __restrict__ W1,
                                                   const float* __restrict__ W2,
                                                   ushort* __restrict__ Wp1,
                                                   ushort* __restrict__ Wp2) {
  int idx = blockIdx.x * 256 + threadIdx.x;  // 0..32767
  const float* W = (idx < 16384) ? W1 : W2;
  ushort* Wp = (idx < 16384) ? Wp1 : Wp2;
  int t = idx & 16383;
  int b = t & 7, i = (t >> 3) & 15, g = (t >> 7) & 3, kt = (t >> 9) & 3, ct = t >> 11;
  int k = kt * 32 + g * 8 + b, col = ct * 16 + i;
  Wp[t] = f2bf(W[k * 128 + col]);
}

// ---------------- MFMA GEMM + fused scores (+ optional fused BN+SELU on X load) ---------
template <int HEADS, bool BN>
__global__ __launch_bounds__(256) void gemm_mfma_kernel(
    const float* __restrict__ X, const ushort* __restrict__ Wp, ushort* __restrict__ H,
    const float* __restrict__ asr, const float* __restrict__ adt,
    float* __restrict__ ssrc, float* __restrict__ sdst, int n,
    const float* __restrict__ stats, const float* __restrict__ gamma,
    const float* __restrict__ beta) {
  __shared__ float sc[128], sh[128];
  if (BN) {
    int t = threadIdx.x;
    if (t < 128) {
      float invN = 1.0f / (float)n;
      float mu = stats[t] * invN;
      float var = stats[128 + t] * invN - mu * mu;
      float rs = rsqrtf(var + 1e-5f);
      float s = gamma[t] * rs;
      sc[t] = s;
      sh[t] = beta[t] - s * mu;
    }
    __syncthreads();
  }
  const int tid = threadIdx.x;
  const int w = tid >> 6, l = tid & 63;
  const int lj = l & 15, lg = l >> 4;
  const int row = blockIdx.x * 64 + w * 16 + lj;
  const bool rowok = row < n;
  const float* xrow = X + (size_t)row * 128;

  f32x4 acc[8];
#pragma unroll
  for (int ct = 0; ct < 8; ++ct) acc[ct] = (f32x4){0.f, 0.f, 0.f, 0.f};

#pragma unroll
  for (int kt = 0; kt < 4; ++kt) {
    const int k0 = kt * 32 + lg * 8;
    float4 xa = make_float4(0.f, 0.f, 0.f, 0.f), xb = xa;
    if (rowok) {
      xa = *(const float4*)(xrow + k0);
      xb = *(const float4*)(xrow + k0 + 4);
    }
    float xv[8] = {xa.x, xa.y, xa.z, xa.w, xb.x, xb.y, xb.z, xb.w};
    if (BN) {
#pragma unroll
      for (int b = 0; b < 8; ++b) xv[b] = selu_f(xv[b] * sc[k0 + b] + sh[k0 + b]);
    }
    short8 bx;
#pragma unroll
    for (int b = 0; b < 8; ++b) bx[b] = (short)f2bf(xv[b]);
#pragma unroll
    for (int ct = 0; ct < 8; ++ct) {
      short8 af = *(const short8*)(Wp + ((((ct * 4 + kt) * 4 + lg) * 16 + lj) << 3));
      acc[ct] = __builtin_amdgcn_mfma_f32_16x16x32_bf16(af, bx, acc[ct], 0, 0, 0);
    }
  }

  if (rowok) {
#pragma unroll
    for (int ct = 0; ct < 8; ++ct) {
      ushort4 h4;
      h4.x = f2bf(acc[ct][0]);
      h4.y = f2bf(acc[ct][1]);
      h4.z = f2bf(acc[ct][2]);
      h4.w = f2bf(acc[ct][3]);
      *(ushort4*)&H[(size_t)row * 128 + ct * 16 + lg * 4] = h4;
    }
  }

  if (HEADS == 8) {
    float ps[8], pd[8];
#pragma unroll
    for (int ct = 0; ct < 8; ++ct) {
      float4 av = *(const float4*)&asr[ct * 16 + lg * 4];
      float4 dv = *(const float4*)&adt[ct * 16 + lg * 4];
      ps[ct] = acc[ct][0] * av.x + acc[ct][1] * av.y + acc[ct][2] * av.z + acc[ct][3] * av.w;
      pd[ct] = acc[ct][0] * dv.x + acc[ct][1] * dv.y + acc[ct][2] * dv.z + acc[ct][3] * dv.w;
      ps[ct] += __shfl_xor(ps[ct], 16);
      ps[ct] += __shfl_xor(ps[ct], 32);
      pd[ct] += __shfl_xor(pd[ct], 16);
      pd[ct] += __shfl_xor(pd[ct], 32);
    }
    if (lg == 0 && rowok) {
      *(float4*)&ssrc[(size_t)row * 8] = make_float4(ps[0], ps[1], ps[2], ps[3]);
      *(float4*)&ssrc[(size_t)row * 8 + 4] = make_float4(ps[4], ps[5], ps[6], ps[7]);
      *(float4*)&sdst[(size_t)row * 8] = make_float4(pd[0], pd[1], pd[2], pd[3]);
      *(float4*)&sdst[(size_t)row * 8 + 4] = make_float4(pd[4], pd[5], pd[6], pd[7]);
    }
  } else {
    float ps = 0.f, pd = 0.f;
#pragma unroll
    for (int ct = 0; ct < 8; ++ct) {
      float4 av = *(const float4*)&asr[ct * 16 + lg * 4];
      float4 dv = *(const float4*)&adt[ct * 16 + lg * 4];
      ps += acc[ct][0] * av.x + acc[ct][1] * av.y + acc[ct][2] * av.z + acc[ct][3] * av.w;
      pd += acc[ct][0] * dv.x + acc[ct][1] * dv.y + acc[ct][2] * dv.z + acc[ct][3] * dv.w;
    }
    ps += __shfl_xor(ps, 16);
    ps += __shfl_xor(ps, 32);
    pd += __shfl_xor(pd, 16);
    pd += __shfl_xor(pd, 32);
    if (lg == 0 && rowok) {
      ssrc[row] = ps;
      sdst[row] = pd;
    }
  }
}

// ---------------- CSR build, pass 1: bucket edges by dst>>10 ----------------
// entry = (src << 10) | (dst & 1023)  (n <= 65536)
__global__ __launch_bounds__(256) void bucket_kernel(const int* __restrict__ ei,
                                                     int* __restrict__ gcur,
                                                     uint* __restrict__ bucket,
                                                     int nE, int EA, int NB) {
  __shared__ int lcnt[64];
  __shared__ int lbase[64];
  int tid = threadIdx.x;
  if (tid < 64) lcnt[tid] = 0;
  __syncthreads();
  int e0 = blockIdx.x * 1024;
  uint ent[4];
  int bk[4], lp[4];
#pragma unroll
  for (int j = 0; j < 4; ++j) {
    int e = e0 + j * 256 + tid;
    bk[j] = -1;
    if (e < EA) {
      int src, dst;
      if (e < nE) {
        src = ei[e];
        dst = ei[nE + e];
      } else {
        src = dst = e - nE;
      }
      bk[j] = dst >> 10;
      ent[j] = ((uint)src << 10) | (uint)(dst & 1023);
      lp[j] = atomicAdd(&lcnt[bk[j]], 1);
    }
  }
  __syncthreads();
  if (tid < NB && lcnt[tid] > 0) lbase[tid] = atomicAdd(&gcur[tid], lcnt[tid]);
  __syncthreads();
#pragma unroll
  for (int j = 0; j < 4; ++j) {
    if (bk[j] >= 0) bucket[(size_t)bk[j] * BCAP + lbase[bk[j]] + lp[j]] = ent[j];
  }
}

// ---------------- CSR build, pass 2: per-bucket degree count + scan + fill ----------------
// One block per bucket. Writes offs[] for its 1024 nodes and csr[base..base+cnt).
__global__ __launch_bounds__(1024) void csrbuild_kernel(const int* __restrict__ gcur,
                                                        const uint* __restrict__ bucket,
                                                        int* __restrict__ offs,
                                                        int* __restrict__ csr,
                                                        int n, int NB) {
  __shared__ int ldeg[1024];
  __shared__ int loff[1024];
  __shared__ int lwsum[16];
  __shared__ int sbase;
  int b = blockIdx.x, tid = threadIdx.x;
  int lane = tid & 63, w = tid >> 6;
  // exclusive prefix of bucket totals -> base for this bucket
  if (tid < 64) {
    int v = (tid < NB) ? gcur[tid] : 0;
    int x = v;
#pragma unroll
    for (int s = 1; s < 64; s <<= 1) {
      int t = __shfl_up(x, s);
      if (tid >= s) x += t;
    }
    if (tid == b) sbase = x - v;
  }
  ldeg[tid] = 0;
  __syncthreads();
  int base = sbase;
  int cnt = gcur[b];
  const uint* bb = bucket + (size_t)b * BCAP;
  for (int k = tid; k < cnt; k += 1024) atomicAdd(&ldeg[bb[k] & 1023], 1);
  __syncthreads();
  // block-wide exclusive scan of ldeg[1024]
  int v = ldeg[tid];
  int x = v;
#pragma unroll
  for (int s = 1; s < 64; s <<= 1) {
    int t = __shfl_up(x, s);
    if (lane >= s) x += t;
  }
  if (lane == 63) lwsum[w] = x;
  __syncthreads();
  if (w == 0 && lane < 16) {
    int wv = lwsum[lane];
    int y = wv;
#pragma unroll
    for (int s = 1; s < 16; s <<= 1) {
      int t = __shfl_up(y, s);
      if (lane >= s) y += t;
    }
    lwsum[lane] = y - wv;  // exclusive
  }
  __syncthreads();
  int excl = x - v + lwsum[w];
  loff[tid] = excl;
  int node = b * 1024 + tid;
  if (node < n) offs[node] = base + excl;
  if (b == NB - 1 && tid == 0) offs[n] = base + cnt;
  __syncthreads();
  // reuse ldeg as cursor
  ldeg[tid] = loff[tid];
  __syncthreads();
  for (int k = tid; k < cnt; k += 1024) {
    uint e = bb[k];
    int pos = atomicAdd(&ldeg[e & 1023], 1);
    csr[base + pos] = (int)(e >> 10);
  }
}

// ---------------- aggregation (fused softmax): one node per wave, even/odd halves -------
__global__ __launch_bounds__(256) void agg1_kernel(const ushort* __restrict__ h1,
                                                   const int* __restrict__ csr,
                                                   const int* __restrict__ offs,
                                                   const float* __restrict__ ssrc,
                                                   const float* __restrict__ sdst,
                                                   const float* __restrict__ bias,
                                                   float* __restrict__ out, int nN) {
  int wid = (blockIdx.x * blockDim.x + threadIdx.x) >> 6;  // node
  int lane = threadIdx.x & 63;
  int half = lane >> 5, ll = lane & 31;
  if (wid >= nN) return;
  int c = ll * 4;   // 4 channels per lane
  int h = ll >> 2;  // head = c/16
  float sd = sdst[wid * 8 + h];
  int beg = offs[wid];
  int deg = offs[wid + 1] - beg;
  float a0 = 0.f, a1 = 0.f, a2 = 0.f, a3 = 0.f, den = 0.f;
  int i = half;
  for (; i + 6 < deg; i += 8) {
    int s0 = csr[beg + i];
    int s1 = csr[beg + i + 2];
    int s2 = csr[beg + i + 4];
    int s3 = csr[beg + i + 6];
    float e0 = ssrc[s0 * 8 + h];
    float e1 = ssrc[s1 * 8 + h];
    float e2 = ssrc[s2 * 8 + h];
    float e3 = ssrc[s3 * 8 + h];
    ushort4 u0 = *(const ushort4*)&h1[(size_t)s0 * 128 + c];
    ushort4 u1 = *(const ushort4*)&h1[(size_t)s1 * 128 + c];
    ushort4 u2 = *(const ushort4*)&h1[(size_t)s2 * 128 + c];
    ushort4 u3 = *(const ushort4*)&h1[(size_t)s3 * 128 + c];
    float A0 = __expf(leaky02(e0 + sd));
    float A1 = __expf(leaky02(e1 + sd));
    float A2 = __expf(leaky02(e2 + sd));
    float A3 = __expf(leaky02(e3 + sd));
    a0 += A0 * bf2f(u0.x) + A1 * bf2f(u1.x) + A2 * bf2f(u2.x) + A3 * bf2f(u3.x);
    a1 += A0 * bf2f(u0.y) + A1 * bf2f(u1.y) + A2 * bf2f(u2.y) + A3 * bf2f(u3.y);
    a2 += A0 * bf2f(u0.z) + A1 * bf2f(u1.z) + A2 * bf2f(u2.z) + A3 * bf2f(u3.z);
    a3 += A0 * bf2f(u0.w) + A1 * bf2f(u1.w) + A2 * bf2f(u2.w) + A3 * bf2f(u3.w);
    den += (A0 + A1) + (A2 + A3);
  }
  for (; i < deg; i += 2) {
    int s0 = csr[beg + i];
    float e0 = ssrc[s0 * 8 + h];
    ushort4 u0 = *(const ushort4*)&h1[(size_t)s0 * 128 + c];
    float A0 = __expf(leaky02(e0 + sd));
    a0 += A0 * bf2f(u0.x);
    a1 += A0 * bf2f(u0.y);
    a2 += A0 * bf2f(u0.z);
    a3 += A0 * bf2f(u0.w);
    den += A0;
  }
  a0 += __shfl_xor(a0, 32);
  a1 += __shfl_xor(a1, 32);
  a2 += __shfl_xor(a2, 32);
  a3 += __shfl_xor(a3, 32);
  den += __shfl_xor(den, 32);
  if (half == 0) {
    float invd = 1.0f / (den + 1e-16f);
    float4 bv = *(const float4*)&bias[c];
    *(float4*)&out[(size_t)wid * 128 + c] =
        make_float4(a0 * invd + bv.x, a1 * invd + bv.y, a2 * invd + bv.z, a3 * invd + bv.w);
  }
}

__global__ __launch_bounds__(256) void agg2_kernel(const ushort* __restrict__ h2,
                                                   const int* __restrict__ csr,
                                                   const int* __restrict__ offs,
                                                   const float* __restrict__ ssrc,
                                                   const float* __restrict__ sdst,
                                                   const float* __restrict__ bias,
                                                   float* __restrict__ out, int nN) {
  int wid = (blockIdx.x * blockDim.x + threadIdx.x) >> 6;
  int lane = threadIdx.x & 63;
  int half = lane >> 5, ll = lane & 31;
  if (wid >= nN) return;
  int c = ll * 4;
  float sd = sdst[wid];
  int beg = offs[wid];
  int deg = offs[wid + 1] - beg;
  float a0 = 0.f, a1 = 0.f, a2 = 0.f, a3 = 0.f, den = 0.f;
  int i = half;
  for (; i + 6 < deg; i += 8) {
    int s0 = csr[beg + i];
    int s1 = csr[beg + i + 2];
    int s2 = csr[beg + i + 4];
    int s3 = csr[beg + i + 6];
    float e0 = ssrc[s0];
    float e1 = ssrc[s1];
    float e2 = ssrc[s2];
    float e3 = ssrc[s3];
    ushort4 u0 = *(const ushort4*)&h2[(size_t)s0 * 128 + c];
    ushort4 u1 = *(const ushort4*)&h2[(size_t)s1 * 128 + c];
    ushort4 u2 = *(const ushort4*)&h2[(size_t)s2 * 128 + c];
    ushort4 u3 = *(const ushort4*)&h2[(size_t)s3 * 128 + c];
    float A0 = __expf(leaky02(e0 + sd));
    float A1 = __expf(leaky02(e1 + sd));
    float A2 = __expf(leaky02(e2 + sd));
    float A3 = __expf(leaky02(e3 + sd));
    a0 += A0 * bf2f(u0.x) + A1 * bf2f(u1.x) + A2 * bf2f(u2.x) + A3 * bf2f(u3.x);
    a1 += A0 * bf2f(u0.y) + A1 * bf2f(u1.y) + A2 * bf2f(u2.y) + A3 * bf2f(u3.y);
    a2 += A0 * bf2f(u0.z) + A1 * bf2f(u1.z) + A2 * bf2f(u2.z) + A3 * bf2f(u3.z);
    a3 += A0 * bf2f(u0.w) + A1 * bf2f(u1.w) + A2 * bf2f(u2.w) + A3 * bf2f(u3.w);
    den += (A0 + A1) + (A2 + A3);
  }
  for (; i < deg; i += 2) {
    int s0 = csr[beg + i];
    float e0 = ssrc[s0];
    ushort4 u0 = *(const ushort4*)&h2[(size_t)s0 * 128 + c];
    float A0 = __expf(leaky02(e0 + sd));
    a0 += A0 * bf2f(u0.x);
    a1 += A0 * bf2f(u0.y);
    a2 += A0 * bf2f(u0.z);
    a3 += A0 * bf2f(u0.w);
    den += A0;
  }
  a0 += __shfl_xor(a0, 32);
  a1 += __shfl_xor(a1, 32);
  a2 += __shfl_xor(a2, 32);
  a3 += __shfl_xor(a3, 32);
  den += __shfl_xor(den, 32);
  if (half == 0) {
    float invd = 1.0f / (den + 1e-16f);
    float4 bv = *(const float4*)&bias[c];
    *(float4*)&out[(size_t)wid * 128 + c] =
        make_float4(a0 * invd + bv.x, a1 * invd + bv.y, a2 * invd + bv.z, a3 * invd + bv.w);
  }
}

// ---------------- column stats (sum, sumsq) for BatchNorm: 64 rows/block ----------------
__global__ __launch_bounds__(256) void stats_kernel(const float* __restrict__ X,
                                                    float* __restrict__ stats, int n) {
  __shared__ float red[256];
  int tid = threadIdx.x;
  int c = tid & 127;
  int half = tid >> 7;
  float s = 0.f, sq = 0.f;
  int rbeg = (int)blockIdx.x * 64 + half;
  int rend = min((int)(blockIdx.x + 1) * 64, n);
#pragma unroll 4
  for (int r = rbeg; r < rend; r += 2) {
    float v = X[(size_t)r * 128 + c];
    s += v;
    sq += v * v;
  }
  red[tid] = s;
  __syncthreads();
  float s2 = (half == 0) ? s + red[tid + 128] : 0.f;
  __syncthreads();
  red[tid] = sq;
  __syncthreads();
  if (half == 0) {
    float sq2 = sq + red[tid + 128];
    atomicAdd(&stats[c], s2);
    atomicAdd(&stats[128 + c], sq2);
  }
}

// ---------------- BatchNorm (batch stats, biased var) + SELU ----------------
__global__ __launch_bounds__(256) void bnselu_kernel(const float* __restrict__ X,
                                                     const float* __restrict__ stats,
                                                     const float* __restrict__ gamma,
                                                     const float* __restrict__ beta,
                                                     float* __restrict__ Y, int n) {
  int gid = blockIdx.x * blockDim.x + threadIdx.x;
  if (gid >= n * 32) return;
  int c = (gid & 31) * 4;
  int r = gid >> 5;
  float invN = 1.0f / (float)n;
  float4 x = *(const float4*)&X[(size_t)r * 128 + c];
  float o[4];
#pragma unroll
  for (int j = 0; j < 4; ++j) {
    float xx = (j == 0) ? x.x : (j == 1) ? x.y : (j == 2) ? x.z : x.w;
    float mu = stats[c + j] * invN;
    float var = stats[128 + c + j] * invN - mu * mu;
    float rs = rsqrtf(var + 1e-5f);
    float y = gamma[c + j] * ((xx - mu) * rs) + beta[c + j];
    o[j] = selu_f(y);
  }
  *(float4*)&Y[(size_t)r * 128 + c] = make_float4(o[0], o[1], o[2], o[3]);
}

extern "C" void kernel_launch(void* const* d_in, const int* in_sizes, int n_in,
                              void* d_out, int out_size, void* d_ws, size_t ws_size,
                              hipStream_t stream) {
  const float* x   = (const float*)d_in[0];
  const int*   ei  = (const int*)d_in[1];
  // d_in[2] = edge_attr: unused (edge_dim=None)
  const float* W1  = (const float*)d_in[3];
  const float* as1 = (const float*)d_in[4];
  const float* ad1 = (const float*)d_in[5];
  const float* b1  = (const float*)d_in[6];
  const float* g1  = (const float*)d_in[7];
  const float* be1 = (const float*)d_in[8];
  const float* W2  = (const float*)d_in[9];
  const float* as2 = (const float*)d_in[10];
  const float* ad2 = (const float*)d_in[11];
  const float* b2  = (const float*)d_in[12];
  const float* g2  = (const float*)d_in[13];
  const float* be2 = (const float*)d_in[14];
  float* out = (float*)d_out;

  const int n  = in_sizes[0] / 128;   // 50000
  const int nE = in_sizes[1] / 2;     // 800000
  const int EA = nE + n;              // 850000
  const int NB = (n + 1023) >> 10;    // 49 dst buckets

  float* ws = (float*)d_ws;
  size_t o = 0;
  float* Bf = ws + o;     o += (size_t)n * 128;   // fp32: agg output / BN input
  ushort* H = (ushort*)(ws + o); o += (size_t)n * 64;  // bf16 h (gather table, reused)
  float* ssrc1 = ws + o;  o += (size_t)n * 8;
  float* sdst1 = ws + o;  o += (size_t)n * 8;
  float* ssrc2 = ws + o;  o += n;
  float* sdst2 = ws + o;  o += n;
  ushort* Wp1 = (ushort*)(ws + o); o += 8192;     // 16384 bf16
  ushort* Wp2 = (ushort*)(ws + o); o += 8192;
  // ---- zero region start ----
  float* zbase = ws + o;
  float* stats1 = ws + o; o += 256;
  float* stats2 = ws + o; o += 256;
  int* gcur = (int*)(ws + o); o += 64;
  size_t zwords = (size_t)((ws + o) - zbase);
  // ---- zero region end ----
  int* offs = (int*)(ws + o); o += (size_t)n + 1;
  int* csr  = (int*)(ws + o); o += EA;
  uint* bucket = (uint*)(ws + o); o += (size_t)NB * BCAP;

  hipMemsetAsync(zbase, 0, zwords * sizeof(float), stream);

  // CSR build (bucketed, shared by both layers) + weight pack
  bucket_kernel<<<(EA + 1023) / 1024, 256, 0, stream>>>(ei, gcur, bucket, nE, EA, NB);
  csrbuild_kernel<<<NB, 1024, 0, stream>>>(gcur, bucket, offs, csr, n, NB);
  pack_kernel<<<128, 256, 0, stream>>>(W1, W2, Wp1, Wp2);

  // ---- layer 1 (GEMM + fused scores) ----
  gemm_mfma_kernel<8, false><<<(n + 63) / 64, 256, 0, stream>>>(
      x, Wp1, H, as1, ad1, ssrc1, sdst1, n, nullptr, nullptr, nullptr);
  agg1_kernel<<<(n + 3) / 4, 256, 0, stream>>>(H, csr, offs, ssrc1, sdst1, b1, Bf, n);
  stats_kernel<<<(n + 63) / 64, 256, 0, stream>>>(Bf, stats1, n);

  // ---- layer 2 (BN+SELU fused into GEMM2 X load; GEMM + fused scores) ----
  gemm_mfma_kernel<1, true><<<(n + 63) / 64, 256, 0, stream>>>(
      Bf, Wp2, H, as2, ad2, ssrc2, sdst2, n, stats1, g1, be1);
  agg2_kernel<<<(n + 3) / 4, 256, 0, stream>>>(H, csr, offs, ssrc2, sdst2, b2, out, n);
  stats_kernel<<<(n + 63) / 64, 256, 0, stream>>>(out, stats2, n);
  bnselu_kernel<<<(n * 32 + 255) / 256, 256, 0, stream>>>(out, stats2, g2, be2, out, n);
}